// Round 5
// baseline (337.717 us; speedup 1.0000x reference)
//
#include <hip/hip_runtime.h>

namespace {

constexpr int H  = 1080;
constexpr int W  = 1920;
constexpr int OH = 270;    // ceil(0.25 * 1080)
constexpr int OW = 480;    // ceil(0.25 * 1920)
constexpr int KT = 16;     // taps per output
constexpr int G  = 7;      // output rows per chunk; oh 2..267 in 38 chunks
constexpr int NCHUNK = 38;
constexpr int VSTRIDE = 1028;  // vbuf row stride in floats

constexpr int EDGE_FULL = 4 * OW;                    // 1920
constexpr int EDGE_TOT  = EDGE_FULL + (OH - 4) * 4;  // 2984
constexpr int EDGE_YS   = 6;   // 6 y-slices x 2 x-blocks x 256 = 3072 >= 2984

// ---------------------------------------------------------------------------
// Fused kernel.
//  by <  NCHUNK : interior tile (vertical polyphase -> LDS -> horizontal).
//  by >= NCHUNK : edge pixels (table-driven gather, validated R3).
// Interior contiguity of taps (rows 4*oh-6.., cols 4*ow-6..) and identical
// interior weight rows validated in R3/R4.
// ---------------------------------------------------------------------------
__global__ __launch_bounds__(256) void bicubic_fused(
    const float* __restrict__ x,    // [BC, H, W]
    const float* __restrict__ wh,   // [OH, KT]
    const int*   __restrict__ ih,   // [OH, KT]
    const float* __restrict__ ww,   // [OW, KT]
    const int*   __restrict__ iw,   // [OW, KT]
    float*       __restrict__ out)  // [BC, OH, OW]
{
    __shared__ float vbuf[G * VSTRIDE];   // 28.8 KB

    const int tid = threadIdx.x;
    const int bx  = blockIdx.x;
    const int by  = blockIdx.y;
    const int bc  = blockIdx.z;

    if (by >= NCHUNK) {
        // ---------------- edge path ----------------
        const int e   = (by - NCHUNK) * 2 + bx;
        const int idx = e * 256 + tid;
        if (idx >= EDGE_TOT) return;

        int oh, ow;
        if (idx < EDGE_FULL) {
            int q = idx / OW;
            ow = idx - q * OW;
            oh = (q < 2) ? q : OH - 4 + q;
        } else {
            int t = idx - EDGE_FULL;
            int q = t & 3;
            oh = 2 + (t >> 2);
            ow = (q < 2) ? q : OW - 4 + q;
        }

        const float* __restrict__ img = x + (size_t)bc * ((size_t)H * W);

        float wt[KT];
        __builtin_memcpy(wt, ww + (size_t)ow * KT, sizeof(wt));
        int ir[KT];
        __builtin_memcpy(ir, iw + (size_t)ow * KT, sizeof(ir));

        bool fastc = true;
        #pragma unroll
        for (int k = 1; k < KT; ++k) fastc = fastc && (ir[k] == ir[0] + k);
        const int i0 = ir[0];

        float acc = 0.0f;
        #pragma unroll 4
        for (int kh = 0; kh < KT; ++kh) {
            const int   r = ih[oh * KT + kh];
            const float w = wh[oh * KT + kh];
            const float* row = img + (size_t)r * W;
            float h = 0.0f;
            if (fastc) {
                float v[KT];
                __builtin_memcpy(v, row + i0, sizeof(v));
                #pragma unroll
                for (int k = 0; k < KT; ++k) h = fmaf(v[k], wt[k], h);
            } else {
                #pragma unroll
                for (int k = 0; k < KT; ++k) h = fmaf(row[ir[k]], wt[k], h);
            }
            acc = fmaf(w, h, acc);
        }
        out[((size_t)bc * OH + oh) * OW + ow] = acc;
        return;
    }

    // ---------------- interior path ----------------
    const int owb = bx ? 254 : 2;       // output-col tile base
    const int Nw  = bx ? 224 : 252;     // outputs in this tile
    const int c0  = 4 * owb - 8;        // staged col base: 0 / 1008 (16B-aligned)
    const int oh0 = 2 + G * by;
    const int r0  = 4 * oh0 - 6;

    // vertical weights (interior rows identical; oh0 wave-uniform -> s_load)
    float wr[KT];
    __builtin_memcpy(wr, wh + (size_t)oh0 * KT, sizeof(wr));

    // this thread's 4 input columns (16B-aligned; clamp only dups tail cols
    // whose LDS slots no valid output reads)
    int c = c0 + 4 * tid;
    if (c > W - 4) c = W - 4;
    const float* __restrict__ p =
        x + ((size_t)bc * H + (size_t)r0) * W + c;

    float acc[4][4];
    #pragma unroll
    for (int m = 0; m < 4; ++m)
        #pragma unroll
        for (int cc = 0; cc < 4; ++cc) acc[m][cc] = 0.0f;

    // prime: load row-group 0
    float cur[4][4];
    #pragma unroll
    for (int pp = 0; pp < 4; ++pp)
        __builtin_memcpy(cur[pp], p + (size_t)pp * W, 16);
    p += (size_t)4 * W;

    #pragma unroll 1                    // forbid unroll: caps loads in flight
    for (int q = 0; q < G + 3; ++q) {
        float nxt[4][4];
        if (q < G + 2) {                // prefetch next 4-row group
            #pragma unroll
            for (int pp = 0; pp < 4; ++pp)
                __builtin_memcpy(nxt[pp], p + (size_t)pp * W, 16);
            p += (size_t)4 * W;
        }
        // compute on cur while nxt is in flight
        #pragma unroll
        for (int pp = 0; pp < 4; ++pp)
            #pragma unroll
            for (int cc = 0; cc < 4; ++cc) {
                const float v = cur[pp][cc];
                acc[0][cc] = fmaf(wr[pp],      v, acc[0][cc]);
                acc[1][cc] = fmaf(wr[4 + pp],  v, acc[1][cc]);
                acc[2][cc] = fmaf(wr[8 + pp],  v, acc[2][cc]);
                acc[3][cc] = fmaf(wr[12 + pp], v, acc[3][cc]);
            }
        if (q >= 3) {
            // staged col c0+4t lives at LDS index 4t+2 (8B-aligned write)
            __builtin_memcpy(&vbuf[(q - 3) * VSTRIDE + 4 * tid + 2],
                             acc[3], 16);
        }
        #pragma unroll
        for (int cc = 0; cc < 4; ++cc) {
            acc[3][cc] = acc[2][cc];
            acc[2][cc] = acc[1][cc];
            acc[1][cc] = acc[0][cc];
            acc[0][cc] = 0.0f;
        }
        if (q < G + 2) {
            #pragma unroll
            for (int pp = 0; pp < 4; ++pp)
                #pragma unroll
                for (int cc = 0; cc < 4; ++cc) cur[pp][cc] = nxt[pp][cc];
        }
    }
    __syncthreads();

    // -------- horizontal pass: window for ow=owb+t starts at LDS 4t+4 (16B) --
    if (tid < Nw) {
        const int ow = owb + tid;
        float wt[KT];
        __builtin_memcpy(wt, ww + (size_t)ow * KT, sizeof(wt));
        float* __restrict__ obase =
            out + ((size_t)bc * OH + oh0) * OW + ow;
        #pragma unroll
        for (int t = 0; t < G; ++t) {
            float v[KT];
            __builtin_memcpy(v, &vbuf[t * VSTRIDE + 4 * tid + 4], sizeof(v));
            float s0 = 0.f, s1 = 0.f;
            #pragma unroll
            for (int k = 0; k < KT; k += 2) {
                s0 = fmaf(v[k],     wt[k],     s0);
                s1 = fmaf(v[k + 1], wt[k + 1], s1);
            }
            obase[(size_t)t * OW] = s0 + s1;
        }
    }
}

// ---------------------------------------------------------------------------
// Safety net for unexpected tap counts.
// ---------------------------------------------------------------------------
__global__ __launch_bounds__(256) void bicubic_generic(
    const float* __restrict__ x,
    const float* __restrict__ wh,
    const int*   __restrict__ ih,
    const float* __restrict__ ww,
    const int*   __restrict__ iw,
    float*       __restrict__ out,
    int Kh, int Kw, int total)
{
    int t = blockIdx.x * blockDim.x + threadIdx.x;
    if (t >= total) return;
    int ow = t % OW;
    int oh = (t / OW) % OH;
    int bc = t / (OW * OH);
    const float* img = x + (size_t)bc * ((size_t)H * W);
    float acc = 0.0f;
    for (int kh = 0; kh < Kh; ++kh) {
        const int   r = ih[oh * Kh + kh];
        const float w = wh[oh * Kh + kh];
        const float* row = img + (size_t)r * W;
        float h = 0.0f;
        for (int k = 0; k < Kw; ++k)
            h = fmaf(row[iw[ow * Kw + k]], ww[ow * Kw + k], h);
        acc = fmaf(w, h, acc);
    }
    out[t] = acc;
}

} // namespace

extern "C" void kernel_launch(void* const* d_in, const int* in_sizes, int n_in,
                              void* d_out, int out_size, void* d_ws, size_t ws_size,
                              hipStream_t stream) {
    const float* x  = (const float*)d_in[0];
    const float* wh = (const float*)d_in[1];
    const int*   ih = (const int*)d_in[2];
    const float* ww = (const float*)d_in[3];
    const int*   iw = (const int*)d_in[4];
    float*       out = (float*)d_out;

    const int BC = in_sizes[0] / (H * W);   // 24
    const int Kh = in_sizes[1] / OH;
    const int Kw = in_sizes[3] / OW;

    if (Kh == KT && Kw == KT) {
        dim3 grid(2, NCHUNK + EDGE_YS, BC);
        bicubic_fused<<<grid, 256, 0, stream>>>(x, wh, ih, ww, iw, out);
    } else {
        int total = BC * OH * OW;
        bicubic_generic<<<(total + 255) / 256, 256, 0, stream>>>(
            x, wh, ih, ww, iw, out, Kh, Kw, total);
    }
}

// Round 6
// 321.423 us; speedup vs baseline: 1.0507x; 1.0507x over previous
//
#include <hip/hip_runtime.h>

namespace {

constexpr int H  = 1080;
constexpr int W  = 1920;
constexpr int OH = 270;    // ceil(0.25 * 1080)
constexpr int OW = 480;    // ceil(0.25 * 1920)
constexpr int KT = 16;     // taps per output
constexpr int G  = 2;      // output rows per block; oh 2..267 in 133 chunks
constexpr int NCHUNK = 133;
constexpr int ROWS = 4 * G + 12;   // 20 input rows per block
constexpr int VSTRIDE = 1032;      // vbuf row stride in floats

constexpr int EDGE_FULL = 4 * OW;                    // 1920
constexpr int EDGE_TOT  = EDGE_FULL + (OH - 4) * 4;  // 2984
constexpr int EDGE_YS   = 6;   // 6 y-slices x 2 x-blocks x 256 = 3072 >= 2984

// ---------------------------------------------------------------------------
// Fused kernel.
//  by <  EDGE_YS : edge pixels (table-driven gather) — dispatched FIRST so
//                  their latency chains overlap interior work (no tail).
//  by >= EDGE_YS : interior tile. Vertical: 20 fully independent float4 row
//                  loads per thread (max MLP, no loop-carried dependency),
//                  reduced into G=2 accumulator sets -> LDS -> horizontal.
// Tap contiguity (rows 4*oh-6.., cols 4*ow-6..) and identical interior
// weight rows validated R3-R5 (absmax 2e-3).
// ---------------------------------------------------------------------------
__global__ __launch_bounds__(256) void bicubic_fused(
    const float* __restrict__ x,    // [BC, H, W]
    const float* __restrict__ wh,   // [OH, KT]
    const int*   __restrict__ ih,   // [OH, KT]
    const float* __restrict__ ww,   // [OW, KT]
    const int*   __restrict__ iw,   // [OW, KT]
    float*       __restrict__ out)  // [BC, OH, OW]
{
    __shared__ float vbuf[G * VSTRIDE];   // 8.3 KB

    const int tid = threadIdx.x;
    const int bx  = blockIdx.x;
    const int by  = blockIdx.y;
    const int bc  = blockIdx.z;

    if (by < EDGE_YS) {
        // ---------------- edge path ----------------
        const int idx = (by * 2 + bx) * 256 + tid;
        if (idx >= EDGE_TOT) return;

        int oh, ow;
        if (idx < EDGE_FULL) {
            int q = idx / OW;
            ow = idx - q * OW;
            oh = (q < 2) ? q : OH - 4 + q;
        } else {
            int t = idx - EDGE_FULL;
            int q = t & 3;
            oh = 2 + (t >> 2);
            ow = (q < 2) ? q : OW - 4 + q;
        }

        const float* __restrict__ img = x + (size_t)bc * ((size_t)H * W);

        float wt[KT];
        __builtin_memcpy(wt, ww + (size_t)ow * KT, sizeof(wt));
        int ir[KT];
        __builtin_memcpy(ir, iw + (size_t)ow * KT, sizeof(ir));

        bool fastc = true;
        #pragma unroll
        for (int k = 1; k < KT; ++k) fastc = fastc && (ir[k] == ir[0] + k);
        const int i0 = ir[0];

        float acc = 0.0f;
        #pragma unroll
        for (int kh = 0; kh < KT; ++kh) {
            const int   r = ih[oh * KT + kh];
            const float w = wh[oh * KT + kh];
            const float* row = img + (size_t)r * W;
            float h = 0.0f;
            if (fastc) {
                float v[KT];
                __builtin_memcpy(v, row + i0, sizeof(v));
                #pragma unroll
                for (int k = 0; k < KT; ++k) h = fmaf(v[k], wt[k], h);
            } else {
                #pragma unroll
                for (int k = 0; k < KT; ++k) h = fmaf(row[ir[k]], wt[k], h);
            }
            acc = fmaf(w, h, acc);
        }
        out[((size_t)bc * OH + oh) * OW + ow] = acc;
        return;
    }

    // ---------------- interior path ----------------
    const int owb = bx ? 254 : 2;       // output-col tile base
    const int Nw  = bx ? 224 : 252;     // outputs in this tile
    const int c0  = 4 * owb - 8;        // staged col base: 0 / 1008 (16B-aligned)
    const int oh0 = 2 + G * (by - EDGE_YS);   // 2..266
    const int r0  = 4 * oh0 - 6;

    // vertical weights (interior rows identical; oh0 wave-uniform -> s_load)
    float wr[KT];
    __builtin_memcpy(wr, wh + (size_t)oh0 * KT, sizeof(wr));

    // this thread's 4 input columns (16B-aligned; clamped dups land in LDS
    // slots never read by a valid output)
    int c = c0 + 4 * tid;
    if (c > W - 4) c = W - 4;
    const float* __restrict__ p =
        x + ((size_t)bc * H + (size_t)r0) * W + c;

    // 20 independent loads, 2 accumulator sets (out row t uses rows 4t..4t+15)
    float a0[4] = {0.f, 0.f, 0.f, 0.f};
    float a1[4] = {0.f, 0.f, 0.f, 0.f};
    #pragma unroll
    for (int r = 0; r < ROWS; ++r) {
        float v[4];
        __builtin_memcpy(v, p + (size_t)r * W, 16);
        if (r < 16) {
            const float w = wr[r];
            #pragma unroll
            for (int cc = 0; cc < 4; ++cc) a0[cc] = fmaf(w, v[cc], a0[cc]);
        }
        if (r >= 4) {
            const float w = wr[r - 4];
            #pragma unroll
            for (int cc = 0; cc < 4; ++cc) a1[cc] = fmaf(w, v[cc], a1[cc]);
        }
    }
    // staged col c0+4t lives at LDS index 4t+2 (8B-aligned b64 writes)
    __builtin_memcpy(&vbuf[0 * VSTRIDE + 4 * tid + 2], a0, 16);
    __builtin_memcpy(&vbuf[1 * VSTRIDE + 4 * tid + 2], a1, 16);
    __syncthreads();

    // -------- horizontal: window for ow=owb+t starts at LDS 4t+4 (16B) ------
    if (tid < Nw) {
        const int ow = owb + tid;
        float wt[KT];
        __builtin_memcpy(wt, ww + (size_t)ow * KT, sizeof(wt));
        float* __restrict__ obase =
            out + ((size_t)bc * OH + oh0) * OW + ow;
        #pragma unroll
        for (int t = 0; t < G; ++t) {
            float v[KT];
            __builtin_memcpy(v, &vbuf[t * VSTRIDE + 4 * tid + 4], sizeof(v));
            float s0 = 0.f, s1 = 0.f;
            #pragma unroll
            for (int k = 0; k < KT; k += 2) {
                s0 = fmaf(v[k],     wt[k],     s0);
                s1 = fmaf(v[k + 1], wt[k + 1], s1);
            }
            obase[(size_t)t * OW] = s0 + s1;
        }
    }
}

// ---------------------------------------------------------------------------
// Safety net for unexpected tap counts.
// ---------------------------------------------------------------------------
__global__ __launch_bounds__(256) void bicubic_generic(
    const float* __restrict__ x,
    const float* __restrict__ wh,
    const int*   __restrict__ ih,
    const float* __restrict__ ww,
    const int*   __restrict__ iw,
    float*       __restrict__ out,
    int Kh, int Kw, int total)
{
    int t = blockIdx.x * blockDim.x + threadIdx.x;
    if (t >= total) return;
    int ow = t % OW;
    int oh = (t / OW) % OH;
    int bc = t / (OW * OH);
    const float* img = x + (size_t)bc * ((size_t)H * W);
    float acc = 0.0f;
    for (int kh = 0; kh < Kh; ++kh) {
        const int   r = ih[oh * Kh + kh];
        const float w = wh[oh * Kh + kh];
        const float* row = img + (size_t)r * W;
        float h = 0.0f;
        for (int k = 0; k < Kw; ++k)
            h = fmaf(row[iw[ow * Kw + k]], ww[ow * Kw + k], h);
        acc = fmaf(w, h, acc);
    }
    out[t] = acc;
}

} // namespace

extern "C" void kernel_launch(void* const* d_in, const int* in_sizes, int n_in,
                              void* d_out, int out_size, void* d_ws, size_t ws_size,
                              hipStream_t stream) {
    const float* x  = (const float*)d_in[0];
    const float* wh = (const float*)d_in[1];
    const int*   ih = (const int*)d_in[2];
    const float* ww = (const float*)d_in[3];
    const int*   iw = (const int*)d_in[4];
    float*       out = (float*)d_out;

    const int BC = in_sizes[0] / (H * W);   // 24
    const int Kh = in_sizes[1] / OH;
    const int Kw = in_sizes[3] / OW;

    if (Kh == KT && Kw == KT) {
        dim3 grid(2, EDGE_YS + NCHUNK, BC);
        bicubic_fused<<<grid, 256, 0, stream>>>(x, wh, ih, ww, iw, out);
    } else {
        int total = BC * OH * OW;
        bicubic_generic<<<(total + 255) / 256, 256, 0, stream>>>(
            x, wh, ih, ww, iw, out, Kh, Kw, total);
    }
}